// Round 1
// 2043.000 us; speedup vs baseline: 1.1626x; 1.1626x over previous
//
#include <hip/hip_runtime.h>
#include <math.h>

// Problem constants
#define DMODEL 256
#define NHEADS 8
#define NLAY 6
#define DFF 1024
#define DHEAD 32
#define NB 2
#define STOT 21760
#define MTOT (NB * STOT)   // 43520 = 128 * 340

typedef unsigned short u16;
typedef __attribute__((ext_vector_type(8))) short short8;
typedef __attribute__((ext_vector_type(4))) float floatx4;

__device__ __forceinline__ float bf2f(u16 h) {
    unsigned int u = ((unsigned int)h) << 16;
    return __uint_as_float(u);
}
__device__ __forceinline__ u16 f2bf(float f) {
    unsigned int u = __float_as_uint(f);
    u = u + 0x7fffu + ((u >> 16) & 1u);   // RNE
    return (u16)(u >> 16);
}

// ---------------------------------------------------------------------------
// Concatenated bias [NLAY][384] = boff[i] (256) || battn[i] (128)
// ---------------------------------------------------------------------------
__global__ __launch_bounds__(256)
void biascat_kernel(const float* __restrict__ boff, const float* __restrict__ battn,
                    float* __restrict__ bias384)
{
    const int t = blockIdx.x * 256 + threadIdx.x;
    if (t >= NLAY * 384) return;
    const int i = t / 384, c = t - i * 384;
    bias384[t] = (c < 256) ? boff[i * 256 + c] : battn[i * 128 + (c - 256)];
}

// ---------------------------------------------------------------------------
// Weight transpose + bf16 cast: W[K,N] f32 -> Wt[N,K] bf16.
// grid(N/32, K/32, NLAY); separate per-layer strides for src/dst.
// ---------------------------------------------------------------------------
__global__ __launch_bounds__(256)
void wtrans_kernel(const float* __restrict__ W, u16* __restrict__ Wt,
                   const int K, const int N, const long wstride, const long ostride)
{
    __shared__ float ts[32][33];
    W  += blockIdx.z * wstride;
    Wt += blockIdx.z * ostride;
    const int n0 = blockIdx.x * 32;
    const int k0 = blockIdx.y * 32;
    const int t = threadIdx.x;
    const int nl = t & 31, kl = t >> 5;        // kl 0..7
#pragma unroll
    for (int p = 0; p < 4; ++p) {
        const int k = kl + p * 8;
        ts[k][nl] = W[(long)(k0 + k) * N + n0 + nl];
    }
    __syncthreads();
    const int c = t & 31, r0 = t >> 5;
#pragma unroll
    for (int p = 0; p < 4; ++p) {
        const int r = r0 + p * 8;
        Wt[(long)(n0 + r) * K + k0 + c] = f2bf(ts[c][r]);
    }
}

// ---------------------------------------------------------------------------
// Flatten: src[b,d,y,x] -> out f32, outb bf16, posb bf16, qb = bf16(src+pos+le)
// ---------------------------------------------------------------------------
__global__ __launch_bounds__(256)
void flatten_kernel(const float* __restrict__ src, const float* __restrict__ pos,
                    const float* __restrict__ le_row,
                    float* __restrict__ out, u16* __restrict__ outb,
                    u16* __restrict__ posb, u16* __restrict__ qb,
                    int HW, int start)
{
    __shared__ float ts[32][33];
    __shared__ float tp[32][33];
    const int b   = blockIdx.z;
    const int d0  = blockIdx.y * 32;
    const int hw0 = blockIdx.x * 32;
    const int t   = threadIdx.x;
    const int hwl = t & 31;
    const int dl  = t >> 5;
#pragma unroll
    for (int p = 0; p < 4; ++p) {
        const int dd = dl + p * 8;
        const int d  = d0 + dd;
        const long idx = ((long)(b * DMODEL + d)) * HW + hw0 + hwl;
        ts[dd][hwl] = src[idx];
        tp[dd][hwl] = pos[idx] + le_row[d];
    }
    __syncthreads();
    const int dl2  = t & 31;
    const int hwl2 = t >> 5;
#pragma unroll
    for (int p = 0; p < 4; ++p) {
        const int hh  = hwl2 + p * 8;
        const int tok = start + hw0 + hh;
        const long o  = ((long)(b * STOT + tok)) * DMODEL + d0 + dl2;
        const float v = ts[dl2][hh];
        const float pp = tp[dl2][hh];
        out[o]  = v;
        outb[o] = f2bf(v);
        posb[o] = f2bf(pp);
        qb[o]   = f2bf(v + pp);
    }
}

// ---------------------------------------------------------------------------
// bf16 MFMA GEMM: Cb[M,N]bf16 = A[M,K]bf16 @ Bt[N,K]bf16^T + bias (relu opt)
// 128x128 tile, BK=32, 256 thr = 4 waves (2x2), each wave 4x4 of 16x16x32 MFMA.
// If Cb2 != null and n0 >= 256: write to Cb2 with ld 128, col-256 (merged
// off||attn output split).
// ---------------------------------------------------------------------------
__global__ __launch_bounds__(256)
void mfma_gemm(const u16* __restrict__ A, const u16* __restrict__ Bt,
               const int ldb, const float* __restrict__ bias,
               u16* __restrict__ Cb, const int ldc, u16* __restrict__ Cb2,
               const int K, const int relu)
{
    __shared__ u16 As[128 * 40];
    __shared__ u16 Bs[128 * 40];
    const int tid  = threadIdx.x;
    const int wv   = tid >> 6;
    const int lane = tid & 63;
    const int m0 = blockIdx.y * 128;
    const int n0 = blockIdx.x * 128;
    const int wm = (wv & 1) * 64;
    const int wn = (wv >> 1) * 64;
    const int q   = lane >> 4;
    const int c16 = lane & 15;

    const int srow = tid >> 2;        // 0..63
    const int scol = (tid & 3) * 8;   // 0,8,16,24

    floatx4 acc[4][4];
#pragma unroll
    for (int i = 0; i < 4; ++i)
#pragma unroll
        for (int j = 0; j < 4; ++j)
            acc[i][j] = (floatx4){0.f, 0.f, 0.f, 0.f};

    union Frag { short8 v; uint2 u[2]; };

    for (int k0 = 0; k0 < K; k0 += 32) {
#pragma unroll
        for (int it = 0; it < 2; ++it) {
            const int r = srow + it * 64;
            const uint4 va = *(const uint4*)(A + (long)(m0 + r) * K + k0 + scol);
            uint2 lo, hi;
            lo.x = va.x; lo.y = va.y; hi.x = va.z; hi.y = va.w;
            *(uint2*)&As[r * 40 + scol]     = lo;
            *(uint2*)&As[r * 40 + scol + 4] = hi;
            const uint4 vb = *(const uint4*)(Bt + (long)(n0 + r) * ldb + k0 + scol);
            lo.x = vb.x; lo.y = vb.y; hi.x = vb.z; hi.y = vb.w;
            *(uint2*)&Bs[r * 40 + scol]     = lo;
            *(uint2*)&Bs[r * 40 + scol + 4] = hi;
        }
        __syncthreads();

        short8 af[4], bf[4];
#pragma unroll
        for (int i = 0; i < 4; ++i) {
            Frag fa;
            const int ao = (wm + i * 16 + c16) * 40 + q * 8;
            fa.u[0] = *(const uint2*)&As[ao];
            fa.u[1] = *(const uint2*)&As[ao + 4];
            af[i] = fa.v;
            Frag fb;
            const int bo = (wn + i * 16 + c16) * 40 + q * 8;
            fb.u[0] = *(const uint2*)&Bs[bo];
            fb.u[1] = *(const uint2*)&Bs[bo + 4];
            bf[i] = fb.v;
        }
#pragma unroll
        for (int i = 0; i < 4; ++i)
#pragma unroll
            for (int j = 0; j < 4; ++j)
                acc[i][j] = __builtin_amdgcn_mfma_f32_16x16x32_bf16(
                    af[i], bf[j], acc[i][j], 0, 0, 0);
        __syncthreads();
    }

    // output selection (block-uniform)
    u16* cb  = Cb;
    int ldcb = ldc, csub = 0;
    if (Cb2 && n0 >= 256) { cb = Cb2; ldcb = 128; csub = 256; }

#pragma unroll
    for (int i = 0; i < 4; ++i) {
#pragma unroll
        for (int j = 0; j < 4; ++j) {
            const int col = n0 + wn + j * 16 + c16;
            const float bv = bias ? bias[col] : 0.f;
#pragma unroll
            for (int r = 0; r < 4; ++r) {
                const int row = m0 + wm + i * 16 + q * 4 + r;
                float v = acc[i][j][r] + bv;
                if (relu) v = fmaxf(v, 0.f);
                cb[(long)row * ldcb + col - csub] = f2bf(v);
            }
        }
    }
}

// ---------------------------------------------------------------------------
// Deformable sampling, all-bf16 inputs, softmax fused in-register.
// One wave per token: 8 heads x 8 lanes, each lane covers 4 channels with 8B
// gathers. 4 tokens per block.
//
// Key points vs previous version:
//  - branch-free corners: levels are pow2 so clamp = & (lw-1); OOB handled by
//    zeroing the bilinear weight via one unsigned compare per corner axis.
//  - per level, all 16 weights/offsets are computed first, then all 16 uint2
//    gathers are issued back-to-back (16 loads in flight vs ~2 before).
//  - softmax over the 16 logits is done in-register per lane (denominator
//    folded into the final accumulator scale) -> softmax16_kernel removed.
// ---------------------------------------------------------------------------
__global__ __launch_bounds__(256)
void sample_kernel(const u16* __restrict__ value, const u16* __restrict__ offb,
                   const u16* __restrict__ logit, u16* __restrict__ sb)
{
    constexpr int LW[4] = {128, 64, 32, 16};
    constexpr int SH[4] = {7, 6, 5, 4};
    constexpr int LS[4] = {0, 16384, 20480, 21504};

    const int t = threadIdx.x;
    const int tl = t >> 6;                 // token within block (wave id)
    const int tid64 = t & 63;
    const int h = tid64 >> 3;              // head 0..7
    const int lane8 = tid64 & 7;           // 0..7 -> 4 channels each
    const int blk = blockIdx.x * 4 + tl;   // global token
    const int b = blk / STOT;
    const int s = blk - b * STOT;

    float refx, refy;
    if (s < 16384) {
        const int yy = s >> 7, xx = s & 127;
        refx = (xx + 0.5f) * (1.f / 128.f); refy = (yy + 0.5f) * (1.f / 128.f);
    } else if (s < 20480) {
        const int sl = s - 16384; const int yy = sl >> 6, xx = sl & 63;
        refx = (xx + 0.5f) * (1.f / 64.f);  refy = (yy + 0.5f) * (1.f / 64.f);
    } else if (s < 21504) {
        const int sl = s - 20480; const int yy = sl >> 5, xx = sl & 31;
        refx = (xx + 0.5f) * (1.f / 32.f);  refy = (yy + 0.5f) * (1.f / 32.f);
    } else {
        const int sl = s - 21504; const int yy = sl >> 4, xx = sl & 15;
        refx = (xx + 0.5f) * (1.f / 16.f);  refy = (yy + 0.5f) * (1.f / 16.f);
    }

    // ---- fused softmax over this head's 16 logits (numerators only) ----
    const uint* awp = (const uint*)(logit + (long)blk * 128 + h * 16);
    const uint4 la = ((const uint4*)awp)[0];
    const uint4 lb = ((const uint4*)awp)[1];
    const uint lu[8] = {la.x, la.y, la.z, la.w, lb.x, lb.y, lb.z, lb.w};
    float lv[16];
#pragma unroll
    for (int j = 0; j < 8; ++j) {
        lv[2 * j]     = bf2f((u16)(lu[j] & 0xffffu));
        lv[2 * j + 1] = bf2f((u16)(lu[j] >> 16));
    }
    float mx = lv[0];
#pragma unroll
    for (int i = 1; i < 16; ++i) mx = fmaxf(mx, lv[i]);
    float pw[16];
    float se = 0.f;
#pragma unroll
    for (int i = 0; i < 16; ++i) { pw[i] = __expf(lv[i] - mx); se += pw[i]; }
    const float inv = 1.f / se;            // applied once at the end

    const uint* offp = (const uint*)(offb + (long)blk * 256 + h * 32);
    const int ch = h * DHEAD + lane8 * 4;  // first of 4 channels
    const u16* vtok = value + (long)b * STOT * DMODEL + ch;

    float a0 = 0.f, a1 = 0.f, a2 = 0.f, a3 = 0.f;
#pragma unroll
    for (int l = 0; l < 4; ++l) {
        const int lw = LW[l], sh = SH[l];
        const u16* vbase = vtok + (long)LS[l] * DMODEL;
        const uint4 olv = ((const uint4*)offp)[l];   // 4 points x (x,y) bf16
        const uint ou[4] = {olv.x, olv.y, olv.z, olv.w};
        const float fx = refx * lw - 0.5f;
        const float fy = refy * lw - 0.5f;           // square levels: lh == lw

        float w[16];
        int ofs[16];
#pragma unroll
        for (int p = 0; p < 4; ++p) {
            const uint o2 = ou[p];
            const float x = fx + bf2f((u16)(o2 & 0xffffu));
            const float y = fy + bf2f((u16)(o2 >> 16));
            const float x0f = floorf(x), y0f = floorf(y);
            const float lx = x - x0f, ly = y - y0f;
            const int x0 = (int)x0f, y0 = (int)y0f;
            const float aP = pw[l * 4 + p];
            // (uint)v < lw  <=>  v >= 0 && v < lw   (single cmp + cndmask)
            const float wx0 = ((uint)x0 < (uint)lw) ? (1.f - lx) : 0.f;
            const float wx1 = ((uint)(x0 + 1) < (uint)lw) ? lx : 0.f;
            const float wy0 = ((uint)y0 < (uint)lw) ? (aP * (1.f - ly)) : 0.f;
            const float wy1 = ((uint)(y0 + 1) < (uint)lw) ? (aP * ly) : 0.f;
            // pow2 clamp: OOB corners have weight 0, address just needs to be
            // in-range for safety.
            const int xc0 = x0 & (lw - 1), xc1 = (x0 + 1) & (lw - 1);
            const int r0 = (y0 & (lw - 1)) << sh;
            const int r1 = ((y0 + 1) & (lw - 1)) << sh;
            w[p * 4 + 0] = wy0 * wx0; ofs[p * 4 + 0] = r0 + xc0;
            w[p * 4 + 1] = wy0 * wx1; ofs[p * 4 + 1] = r0 + xc1;
            w[p * 4 + 2] = wy1 * wx0; ofs[p * 4 + 2] = r1 + xc0;
            w[p * 4 + 3] = wy1 * wx1; ofs[p * 4 + 3] = r1 + xc1;
        }
        uint2 dv[16];
#pragma unroll
        for (int i = 0; i < 16; ++i)
            dv[i] = *(const uint2*)(vbase + ((long)ofs[i] << 8));
#pragma unroll
        for (int i = 0; i < 16; ++i) {
            const float wi = w[i];
            a0 = fmaf(wi, __uint_as_float(dv[i].x << 16), a0);
            a1 = fmaf(wi, __uint_as_float(dv[i].x & 0xffff0000u), a1);
            a2 = fmaf(wi, __uint_as_float(dv[i].y << 16), a2);
            a3 = fmaf(wi, __uint_as_float(dv[i].y & 0xffff0000u), a3);
        }
    }
    a0 *= inv; a1 *= inv; a2 *= inv; a3 *= inv;
    ushort4 r;
    r.x = f2bf(a0); r.y = f2bf(a1); r.z = f2bf(a2); r.w = f2bf(a3);
    *(ushort4*)(sb + (long)blk * DMODEL + ch) = r;
}

// ---------------------------------------------------------------------------
// out = LayerNorm(out + delta_bf16); writes f32 residual + bf16 outb.
// If qb != null: also writes qb = bf16(LNout + posb) for next layer's q-GEMM.
// ---------------------------------------------------------------------------
__global__ __launch_bounds__(256)
void ln_kernel(float* __restrict__ out, u16* __restrict__ outb,
               u16* __restrict__ qb, const u16* __restrict__ posb,
               const u16* __restrict__ db,
               const float* __restrict__ gamma, const float* __restrict__ beta)
{
    const int wave = threadIdx.x >> 6;
    const int lane = threadIdx.x & 63;
    const long tok = (long)blockIdx.x * 4 + wave;
    float* op = out + tok * DMODEL + lane * 4;
    const float4 xo = *(const float4*)op;
    const ushort4 d4 = *(const ushort4*)(db + tok * DMODEL + lane * 4);
    float x[4] = {xo.x + bf2f(d4.x), xo.y + bf2f(d4.y),
                  xo.z + bf2f(d4.z), xo.w + bf2f(d4.w)};

    float sum = x[0] + x[1] + x[2] + x[3];
#pragma unroll
    for (int o = 32; o >= 1; o >>= 1) sum += __shfl_xor(sum, o);
    const float mean = sum * (1.f / 256.f);

    float vs = 0.f;
#pragma unroll
    for (int i = 0; i < 4; ++i) { const float d2 = x[i] - mean; vs += d2 * d2; }
#pragma unroll
    for (int o = 32; o >= 1; o >>= 1) vs += __shfl_xor(vs, o);
    const float rstd = rsqrtf(vs * (1.f / 256.f) + 1e-5f);

    const float4 g  = *(const float4*)(gamma + lane * 4);
    const float4 be = *(const float4*)(beta + lane * 4);
    float r[4];
    r[0] = (x[0] - mean) * rstd * g.x + be.x;
    r[1] = (x[1] - mean) * rstd * g.y + be.y;
    r[2] = (x[2] - mean) * rstd * g.z + be.z;
    r[3] = (x[3] - mean) * rstd * g.w + be.w;
    float4 rf; rf.x = r[0]; rf.y = r[1]; rf.z = r[2]; rf.w = r[3];
    *(float4*)op = rf;
    ushort4 rb;
    rb.x = f2bf(r[0]); rb.y = f2bf(r[1]); rb.z = f2bf(r[2]); rb.w = f2bf(r[3]);
    *(ushort4*)(outb + tok * DMODEL + lane * 4) = rb;
    if (qb) {
        const ushort4 p4 = *(const ushort4*)(posb + tok * DMODEL + lane * 4);
        ushort4 qv;
        qv.x = f2bf(r[0] + bf2f(p4.x));
        qv.y = f2bf(r[1] + bf2f(p4.y));
        qv.z = f2bf(r[2] + bf2f(p4.z));
        qv.w = f2bf(r[3] + bf2f(p4.w));
        *(ushort4*)(qb + tok * DMODEL + lane * 4) = qv;
    }
}

// ---------------------------------------------------------------------------
extern "C" void kernel_launch(void* const* d_in, const int* in_sizes, int n_in,
                              void* d_out, int out_size, void* d_ws, size_t ws_size,
                              hipStream_t stream)
{
    const float* src[4] = {(const float*)d_in[0], (const float*)d_in[2],
                           (const float*)d_in[4], (const float*)d_in[6]};
    const float* pos[4] = {(const float*)d_in[1], (const float*)d_in[3],
                           (const float*)d_in[5], (const float*)d_in[7]};
    const float* level_embed = (const float*)d_in[8];
    const float* Woff  = (const float*)d_in[9];
    const float* boff  = (const float*)d_in[10];
    const float* Wattn = (const float*)d_in[11];
    const float* battn = (const float*)d_in[12];
    const float* Wval  = (const float*)d_in[13];
    const float* bval  = (const float*)d_in[14];
    const float* Wout  = (const float*)d_in[15];
    const float* bout  = (const float*)d_in[16];
    const float* ln1s  = (const float*)d_in[17];
    const float* ln1b  = (const float*)d_in[18];
    const float* W1    = (const float*)d_in[19];
    const float* b1    = (const float*)d_in[20];
    const float* W2    = (const float*)d_in[21];
    const float* b2    = (const float*)d_in[22];
    const float* ln2s  = (const float*)d_in[23];
    const float* ln2b  = (const float*)d_in[24];

    float* out = (float*)d_out;                       // residual stream f32
    const long MD = (long)MTOT * DMODEL;              // 11,141,120

    // workspace layout (~187 MB)
    u16* outb = (u16*)d_ws;          // [M,256] LN output bf16
    u16* posb = outb + MD;           // [M,256] pos_flat bf16
    u16* qb   = posb + MD;           // [M,256] q = out+pos bf16
    u16* db   = qb + MD;             // [M,256] delta bf16 (attn_out / ff_out)
    u16* vb   = db + MD;             // [M,256] value bf16      (hb region start)
    u16* offb = vb + MD;             // [M,256] offsets bf16
    u16* awb  = offb + MD;           // [M,128] attn logits bf16
    u16* sb   = awb + MD / 2;        // [M,256] sampled bf16
    u16* hb   = vb;                  // [M,1024] FF hidden (aliases vb..sb+pad)
    u16* wts  = vb + 4 * MD;         // bf16 transposed weights
    u16* Wvalt = wts;
    u16* Wofat = Wvalt + 6L * 256 * 256;   // [384,256] per layer: Woff^T||Wattn^T
    u16* Woutt = Wofat + 6L * 384 * 256;
    u16* W1t   = Woutt + 6L * 256 * 256;
    u16* W2t   = W1t   + 6L * 1024 * 256;
    float* bias384 = (float*)(W2t + 6L * 1024 * 256);  // [NLAY][384]

    // ---- weight prep (every call; ~9 MB) ----
    biascat_kernel<<<9, 256, 0, stream>>>(boff, battn, bias384);
    wtrans_kernel<<<dim3(8, 8, 6),  256, 0, stream>>>(Wval,  Wvalt, 256, 256,
                                                      65536, 65536);
    wtrans_kernel<<<dim3(8, 8, 6),  256, 0, stream>>>(Woff,  Wofat, 256, 256,
                                                      65536, 98304);
    wtrans_kernel<<<dim3(4, 8, 6),  256, 0, stream>>>(Wattn, Wofat + 256 * 256,
                                                      256, 128, 32768, 98304);
    wtrans_kernel<<<dim3(8, 8, 6),  256, 0, stream>>>(Wout,  Woutt, 256, 256,
                                                      65536, 65536);
    wtrans_kernel<<<dim3(32, 8, 6), 256, 0, stream>>>(W1,    W1t, 256, 1024,
                                                      262144, 262144);
    wtrans_kernel<<<dim3(8, 32, 6), 256, 0, stream>>>(W2,    W2t, 1024, 256,
                                                      262144, 262144);

    // ---- flatten ----
    {
        const int HW[4] = {16384, 4096, 1024, 256};
        const int ST[4] = {0, 16384, 20480, 21504};
        for (int l = 0; l < 4; ++l) {
            dim3 g(HW[l] / 32, DMODEL / 32, NB);
            flatten_kernel<<<g, 256, 0, stream>>>(src[l], pos[l],
                                                  level_embed + l * DMODEL,
                                                  out, outb, posb, qb, HW[l], ST[l]);
        }
    }

    const dim3 g2(2, MTOT / 128);   // N=256
    const dim3 g3(3, MTOT / 128);   // N=384 (merged off||attn)
    const dim3 g8(8, MTOT / 128);   // N=1024 (FF1)

    for (int i = 0; i < NLAY; ++i) {
        const u16* Wv  = Wvalt + (long)i * 256 * 256;
        const u16* Wqa = Wofat + (long)i * 384 * 256;
        const u16* Wou = Woutt + (long)i * 256 * 256;
        const u16* W1i = W1t   + (long)i * 1024 * 256;
        const u16* W2i = W2t   + (long)i * 256 * 1024;
        const float* bv  = bval + (long)i * 256;
        const float* bqa = bias384 + (long)i * 384;
        const float* bou = bout + (long)i * 256;
        const float* b1i = b1   + (long)i * DFF;
        const float* b2i = b2   + (long)i * 256;

        // value = out @ Wval + bval -> vb bf16
        mfma_gemm<<<g2, 256, 0, stream>>>(outb, Wv, 256, bv,
                                          vb, 256, nullptr, 256, 0);
        // [off | attn logits] = q @ [Woff|Wattn] -> offb bf16, awb bf16
        mfma_gemm<<<g3, 256, 0, stream>>>(qb, Wqa, 256, bqa,
                                          offb, 256, awb, 256, 0);
        // sampling with fused softmax (reads logits directly)
        sample_kernel<<<MTOT / 4, 256, 0, stream>>>(vb, offb, awb, sb);
        // attn_out = s @ Wout + bout -> db bf16
        mfma_gemm<<<g2, 256, 0, stream>>>(sb, Wou, 256, bou,
                                          db, 256, nullptr, 256, 0);
        ln_kernel<<<MTOT / 4, 256, 0, stream>>>(out, outb, nullptr, nullptr, db,
                                                ln1s + (long)i * 256,
                                                ln1b + (long)i * 256);
        // FF: h = relu(out @ W1 + b1) -> hb bf16 [M,1024]
        mfma_gemm<<<g8, 256, 0, stream>>>(outb, W1i, 256, b1i,
                                          hb, 1024, nullptr, 256, 1);
        // ff_out = h @ W2 + b2 -> db bf16
        mfma_gemm<<<g2, 256, 0, stream>>>(hb, W2i, 1024, b2i,
                                          db, 256, nullptr, 1024, 0);
        ln_kernel<<<MTOT / 4, 256, 0, stream>>>(out, outb, qb, posb, db,
                                                ln2s + (long)i * 256,
                                                ln2b + (long)i * 256);
    }
}